// Round 12
// baseline (87.707 us; speedup 1.0000x reference)
//
#include <hip/hip_runtime.h>

// Problem constants (from reference setup_inputs)
#define BB 4096   // batch
#define SS 256    // sequence length
#define FF 64     // features
#define GG 9      // 3*U gate width

#define NEG_LOG2E -1.4426950408889634f
#define TWO_LOG2E  2.8853900817779268f

typedef float f2 __attribute__((ext_vector_type(2)));

#if __has_builtin(__builtin_amdgcn_exp2f)
__device__ __forceinline__ float fast_exp2(float x) { return __builtin_amdgcn_exp2f(x); }
#else
__device__ __forceinline__ float fast_exp2(float x) { return exp2f(x); }
#endif
#if __has_builtin(__builtin_amdgcn_rcpf)
__device__ __forceinline__ float fast_rcp(float x) { return __builtin_amdgcn_rcpf(x); }
#else
__device__ __forceinline__ float fast_rcp(float x) { return 1.0f / x; }
#endif

// DPP helper: quad_perm (CTRL<0x100) and row ops (row_ror:N = 0x120+N).
template <int CTRL>
__device__ __forceinline__ float dpp_f(float v) {
  return __int_as_float(
      __builtin_amdgcn_mov_dpp(__float_as_int(v), CTRL, 0xF, 0xF, true));
}

// lane ^ 16 exchange via ds_swizzle BitMode: offset = (xor<<10)|(or<<5)|and.
__device__ __forceinline__ float swz_xor16(float v) {
  return __int_as_float(
      __builtin_amdgcn_ds_swizzle(__float_as_int(v), (16 << 10) | 0x1F));
}

// -----------------------------------------------------------------------------
// Fully fused GRU — R12: 32 lanes per chain -> 2048 waves -> 2 waves/SIMD.
// R10 (depth-8 prefetch: +2.5us) and R11 (source stagger: -1.5us) proved the
// ~370cy/step stalls are neither load-latency nor ordering: they're pipeline
// bubbles (DPP hazards, trans latency) that only hardware TLP can fill — and
// 16-lane chains capped us at 1 wave/SIMD. 32-lane chains double wave count;
// per-lane work shrinks (2 features); reduce restructured role-split:
//   xor1+xor2 quad butterfly (18 DPP) -> EARLY select 3-of-9 (6 cndmask)
//   -> ror4+ror8 on 3 vals (6 DPP) -> cross-16 ds_swizzle xor16 (3+3 add).
// Bias pre-scaled by 1/32 (power of two: 32-lane reduce restores exactly 1x).
// Gate chain byte-identical to the absmax-0 R9-R11 lineage.
// -----------------------------------------------------------------------------
__global__ __launch_bounds__(64, 2) void fused_gru_kernel(
    const float* __restrict__ x,           // [B,S,F]
    const float* __restrict__ kernel_w,    // [F,9]
    const float* __restrict__ rec_kernel,  // [3,9]
    const float* __restrict__ bias,        // [2,9]
    const float* __restrict__ dense_w,     // [3,10]
    const float* __restrict__ dense_b,     // [10]
    float* __restrict__ out)               // [B,10]
{
  const int lane = threadIdx.x;        // 0..63
  const int l32  = lane & 31;          // feature-pair slot within the chain
  const int u    = lane & 3;           // gate-unit role within the quad
  const int uc   = (u < 3) ? u : 2;    // lane u==3: clamp unit role (benign)
  const int c    = blockIdx.x * 2 + (lane >> 5);   // chain (batch) id

  // ---- input-projection weights for this lane's 2 features (pre-scaled)
  f2 w01[2], w23[2], w45[2], w67[2];
  float w8[2];
#pragma unroll
  for (int e = 0; e < 2; ++e) {
    const float* kw = kernel_w + (l32 * 2 + e) * GG;
    w01[e] = (f2){kw[0] * NEG_LOG2E, kw[1] * NEG_LOG2E};
    w23[e] = (f2){kw[2] * NEG_LOG2E, kw[3] * NEG_LOG2E};
    w45[e] = (f2){kw[4] * NEG_LOG2E, kw[5] * NEG_LOG2E};
    w67[e] = (f2){kw[6] * TWO_LOG2E, kw[7] * TWO_LOG2E};
    w8[e]  = kw[8] * TWO_LOG2E;
  }

  // input bias (+ recurrent bias folded for z/r gates — algebraically exact),
  // pre-scaled and divided by 32 (power of two; 32-lane reduce restores 1x).
  const float Q = 0.03125f;
  const f2 b01q = {(bias[0] + bias[GG + 0]) * NEG_LOG2E * Q,
                   (bias[1] + bias[GG + 1]) * NEG_LOG2E * Q};
  const f2 b23q = {(bias[2] + bias[GG + 2]) * NEG_LOG2E * Q,
                   (bias[3] + bias[GG + 3]) * NEG_LOG2E * Q};
  const f2 b45q = {(bias[4] + bias[GG + 4]) * NEG_LOG2E * Q,
                   (bias[5] + bias[GG + 5]) * NEG_LOG2E * Q};
  const f2 b67q = {bias[6] * TWO_LOG2E * Q, bias[7] * TWO_LOG2E * Q};
  const float b8q = bias[8] * TWO_LOG2E * Q;

  // recurrent weights for this lane's unit (pre-scaled); only the h-gate's
  // recurrent bias stays separate (it sits inside the r-multiplied term).
  float wz[3], wr[3], wh[3];
#pragma unroll
  for (int hh = 0; hh < 3; ++hh) {
    wz[hh] = rec_kernel[hh * GG + uc]     * NEG_LOG2E;
    wr[hh] = rec_kernel[hh * GG + 3 + uc] * NEG_LOG2E;
    wh[hh] = rec_kernel[hh * GG + 6 + uc] * TWO_LOG2E;
  }
  const float rbh = bias[GG + 6 + uc] * TWO_LOG2E;

  float h0 = 0.0f, h1 = 0.0f, h2 = 0.0f, hprev = 0.0f;

  // per-lane x pointer: row (c,s) = 32 float2s; this lane reads float2 #l32.
  const float2* pc = reinterpret_cast<const float2*>(x) + (size_t)c * SS * 32 + l32;

  // depth-8 register ring (16 VGPRs), named buffers, static indexing
  float2 X0, X1, X2, X3, X4, X5, X6, X7;

  auto step = [&](const float2 v) {
    // projection over this lane's 2 features (10 instrs, f2-packed)
    f2 a01 = b01q, a23 = b23q, a45 = b45q, a67 = b67q;
    float a8 = b8q;
    a01 = v.x * w01[0] + a01; a23 = v.x * w23[0] + a23;
    a45 = v.x * w45[0] + a45; a67 = v.x * w67[0] + a67;
    a8 = fmaf(v.x, w8[0], a8);
    a01 = v.y * w01[1] + a01; a23 = v.y * w23[1] + a23;
    a45 = v.y * w45[1] + a45; a67 = v.y * w67[1] + a67;
    a8 = fmaf(v.y, w8[1], a8);

    // quad butterfly: after xor1+xor2 every lane holds 9 quad-sums
    float s0 = a01.x, s1 = a01.y, s2 = a23.x, s3 = a23.y, s4 = a45.x,
          s5 = a45.y, s6 = a67.x, s7 = a67.y, s8 = a8;
    s0 += dpp_f<0xB1>(s0); s1 += dpp_f<0xB1>(s1); s2 += dpp_f<0xB1>(s2);
    s3 += dpp_f<0xB1>(s3); s4 += dpp_f<0xB1>(s4); s5 += dpp_f<0xB1>(s5);
    s6 += dpp_f<0xB1>(s6); s7 += dpp_f<0xB1>(s7); s8 += dpp_f<0xB1>(s8);
    s0 += dpp_f<0x4E>(s0); s1 += dpp_f<0x4E>(s1); s2 += dpp_f<0x4E>(s2);
    s3 += dpp_f<0x4E>(s3); s4 += dpp_f<0x4E>(s4); s5 += dpp_f<0x4E>(s5);
    s6 += dpp_f<0x4E>(s6); s7 += dpp_f<0x4E>(s7); s8 += dpp_f<0x4E>(s8);

    // EARLY role select (3 of 9): all subsequent lane exchanges preserve
    // role (ror4/ror8/xor16 map lane -> lane with same (lane&3)).
    float az = (u == 0) ? s0 : ((u == 1) ? s1 : s2);
    float ar = (u == 0) ? s3 : ((u == 1) ? s4 : s5);
    float sh = (u == 0) ? s6 : ((u == 1) ? s7 : s8);

    // cross-quad within the 16-lane row: rotate-accumulate
    az += dpp_f<0x124>(az); ar += dpp_f<0x124>(ar); sh += dpp_f<0x124>(sh);
    az += dpp_f<0x128>(az); ar += dpp_f<0x128>(ar); sh += dpp_f<0x128>(sh);
    // cross-row (lane ^ 16) via ds_swizzle: full 32-lane sums
    az += swz_xor16(az); ar += swz_xor16(ar); sh += swz_xor16(sh);

    // gate chain (absmax-0 verified math; b0+b1 already inside az/ar)
    const float iz = fmaf(h2, wz[2], fmaf(h1, wz[1], fmaf(h0, wz[0], az)));
    const float ir = fmaf(h2, wr[2], fmaf(h1, wr[1], fmaf(h0, wr[0], ar)));
    const float ih = fmaf(h2, wh[2], fmaf(h1, wh[1], fmaf(h0, wh[0], rbh)));
    const float z = fast_rcp(1.0f + fast_exp2(iz));
    const float r = fast_rcp(1.0f + fast_exp2(ir));
    const float t = fmaf(-2.0f, fast_rcp(1.0f + fast_exp2(fmaf(r, ih, sh))), 1.0f);
    const float hn = fmaf(z, hprev - t, t);
    hprev = hn;
    h0 = dpp_f<0x00>(hn);   // quad_perm [0,0,0,0]
    h1 = dpp_f<0x55>(hn);   // quad_perm [1,1,1,1]
    h2 = dpp_f<0xAA>(hn);   // quad_perm [2,2,2,2]
  };

  // branchless prefetch-index clamp: tail re-reads step SS-1 (L1-hit, free)
  auto pf = [&](int sn) -> float2 {
    sn = (sn < SS) ? sn : (SS - 1);
    return pc[(size_t)sn * 32];
  };

  X0 = pf(0); X1 = pf(1); X2 = pf(2); X3 = pf(3);
  X4 = pf(4); X5 = pf(5); X6 = pf(6); X7 = pf(7);

  for (int sg = 0; sg < SS; sg += 8) {
    step(X0); X0 = pf(sg + 8);
    step(X1); X1 = pf(sg + 9);
    step(X2); X2 = pf(sg + 10);
    step(X3); X3 = pf(sg + 11);
    step(X4); X4 = pf(sg + 12);
    step(X5); X5 = pf(sg + 13);
    step(X6); X6 = pf(sg + 14);
    step(X7); X7 = pf(sg + 15);
  }

  // Dense (3 -> 10) + softmax; quad 0 of each 32-lane chain group writes.
  if (l32 < 4) {
    float lg[10];
#pragma unroll
    for (int j = 0; j < 10; ++j)
      lg[j] = dense_b[j] + h0 * dense_w[j] + h1 * dense_w[10 + j] + h2 * dense_w[20 + j];
    float m = lg[0];
#pragma unroll
    for (int j = 1; j < 10; ++j) m = fmaxf(m, lg[j]);
    float e[10];
    float ssum = 0.0f;
#pragma unroll
    for (int j = 0; j < 10; ++j) {
      e[j] = fast_exp2(1.4426950408889634f * (lg[j] - m));
      ssum += e[j];
    }
    const float inv = fast_rcp(ssum);
#pragma unroll
    for (int j = u; j < 10; j += 4) out[(size_t)c * 10 + j] = e[j] * inv;
  }
}

extern "C" void kernel_launch(void* const* d_in, const int* in_sizes, int n_in,
                              void* d_out, int out_size, void* d_ws, size_t ws_size,
                              hipStream_t stream) {
  const float* x      = (const float*)d_in[0];  // [4096,256,64]
  const float* kern   = (const float*)d_in[1];  // [64,9]
  const float* rkern  = (const float*)d_in[2];  // [3,9]
  const float* bias   = (const float*)d_in[3];  // [2,9]
  const float* dw     = (const float*)d_in[4];  // [3,10]
  const float* db     = (const float*)d_in[5];  // [10]
  float* out = (float*)d_out;

  // 2 chains x 32 lanes per 64-thread block; 2048 blocks -> 2048 waves
  // -> 2 waves per SIMD chip-wide (TLP fills per-wave pipeline bubbles).
  fused_gru_kernel<<<BB / 2, 64, 0, stream>>>(x, kern, rkern, bias, dw, db, out);
}

// Round 13
// 81.661 us; speedup vs baseline: 1.0740x; 1.0740x over previous
//
#include <hip/hip_runtime.h>

// Problem constants (from reference setup_inputs)
#define BB 4096   // batch
#define SS 256    // sequence length
#define FF 64     // features
#define GG 9      // 3*U gate width

#define NEG_LOG2E -1.4426950408889634f
#define TWO_LOG2E  2.8853900817779268f

typedef _Float16 h8 __attribute__((ext_vector_type(8)));
typedef float f4v __attribute__((ext_vector_type(4)));

#if __has_builtin(__builtin_amdgcn_exp2f)
__device__ __forceinline__ float fast_exp2(float x) { return __builtin_amdgcn_exp2f(x); }
#else
__device__ __forceinline__ float fast_exp2(float x) { return exp2f(x); }
#endif
#if __has_builtin(__builtin_amdgcn_rcpf)
__device__ __forceinline__ float fast_rcp(float x) { return __builtin_amdgcn_rcpf(x); }
#else
__device__ __forceinline__ float fast_rcp(float x) { return 1.0f / x; }
#endif

// quad_perm DPP broadcast (verified absmax-0 R3-R12)
template <int CTRL>
__device__ __forceinline__ float dpp_f(float v) {
  return __int_as_float(
      __builtin_amdgcn_mov_dpp(__float_as_int(v), CTRL, 0xF, 0xF, true));
}
// lane ^ MASK exchange via ds_swizzle BitMode (xor is direction-free;
// primitive verified absmax-0 in R12 with MASK=16)
template <int MASK>
__device__ __forceinline__ float swz_xor(float v) {
  return __int_as_float(
      __builtin_amdgcn_ds_swizzle(__float_as_int(v), (MASK << 10) | 0x1F));
}

// B/C column roles: col = 4*U + T; U=unit 0..2 (3=pad), T: 0=z,1=r,2=h (3=pad)
__device__ __forceinline__ float col_w(const float* kw, int k, int col) {
  const int U = col >> 2, T = col & 3;
  if (U > 2 || T > 2) return 0.0f;
  const int g = (T == 0) ? U : ((T == 1) ? 3 + U : 6 + U);
  const float sc = (T == 2) ? TWO_LOG2E : NEG_LOG2E;
  return kw[k * GG + g] * sc;
}

// -----------------------------------------------------------------------------
// Fully fused GRU — R13: MFMA projection. Per wave: 4 chains; per 4-step tile
// ONE 16x16x32_f16 MFMA pair (K=64) computes x@K for 4 chains x 4 steps x 12
// gate-cols, replacing ~288 FMA/DPP instrs (R10) with 2. C-layout (m89-
// verified): quarter=chain, reg=step, col=gate. Cols packed 4*unit+{z,r,h} so
// gate math is quad-local (quad_perm only). Cross-unit h·W gathered with
// direction-free ds_swizzle xor4/8/12. Biases in MFMA C-init; -log2e/2log2e
// folded into B. fp16 inputs (err ~1e-4 << 2.5e-3 threshold).
// Rationale: all compute kernels run ~2x cycle models (throttle-consistent);
// R11/R12 showed reorder/TLP don't pay -> cut instructions 3.7x.
// -----------------------------------------------------------------------------
__global__ __launch_bounds__(64, 1) void fused_gru_kernel(
    const float* __restrict__ x,           // [B,S,F]
    const float* __restrict__ kernel_w,    // [F,9]
    const float* __restrict__ rec_kernel,  // [3,9]
    const float* __restrict__ bias,        // [2,9]
    const float* __restrict__ dense_w,     // [3,10]
    const float* __restrict__ dense_b,     // [10]
    float* __restrict__ out)               // [B,10]
{
  const int l    = threadIdx.x;        // 0..63
  const int col  = l & 15;             // gate column (C-layout)
  const int U    = col >> 2;           // unit (3 = pad)
  const int T    = col & 3;            // 0=z 1=r 2=h (3 = pad)
  const int q    = l >> 4;             // chain quarter (C rows 4q..4q+3)
  const int cbase = blockIdx.x * 4;

  // ---- B fragments (K=64 as two K=32 frags). A/B layout assumption:
  // lane l holds elems k = 8*(l>>4)+e (consecutive k per lane).
  h8 blo, bhi;
#pragma unroll
  for (int e = 0; e < 8; ++e) {
    const int k = (l >> 4) * 8 + e;
    blo[e] = (_Float16)col_w(kernel_w, k, col);
    bhi[e] = (_Float16)col_w(kernel_w, k + 32, col);
  }

  // ---- C init = per-column bias (z/r: b0+b1 folded; h: b0 only; pads 0)
  float cb = 0.0f;
  if (U < 3 && T < 3) {
    const int g = (T == 0) ? U : ((T == 1) ? 3 + U : 6 + U);
    cb = (T == 2) ? bias[g] * TWO_LOG2E
                  : (bias[g] + bias[GG + g]) * NEG_LOG2E;
  }

  // ---- per-lane recurrent weights: w[j] multiplies h from quad U^j
  const int Uc = (U < 3) ? U : 0;
  const int gi = (T == 0) ? Uc : ((T == 1) ? 3 + Uc : 6 + Uc);
  const float sc = (T == 2) ? TWO_LOG2E : NEG_LOG2E;
  float w[4];
#pragma unroll
  for (int j = 0; j < 4; ++j) {
    const int v = U ^ j;
    w[j] = (U < 3 && T < 3 && v < 3) ? rec_kernel[v * GG + gi] * sc : 0.0f;
  }
  const float rbh_s = (T == 2 && U < 3) ? bias[GG + 6 + U] * TWO_LOG2E : 0.0f;

  float hOwn = 0.0f;  // quad-uniform h of unit U (junk in quad 3, weight-0'd)

  // ---- A-source: lane supplies A[row=l&15][k=8*(l>>4)+e]
  // row = 4*chainLocal + stepInTile
  const int arow = l & 15;
  const float* pA = x + (size_t)(cbase + (arow >> 2)) * SS * FF
                      + (arow & 3) * FF + (l >> 4) * 8;

  float4 A0[4], A1[4];  // 2-tile ring (8-step lookahead), static indexing
  auto ldt = [&](float4 (&R)[4], int t) {
    const float* p = pA + (size_t)t * 4 * FF;
    R[0] = *reinterpret_cast<const float4*>(p);
    R[1] = *reinterpret_cast<const float4*>(p + 4);
    R[2] = *reinterpret_cast<const float4*>(p + 32);
    R[3] = *reinterpret_cast<const float4*>(p + 36);
  };
  auto cvt = [](const float4 a, const float4 b) -> h8 {
    h8 r;
    r[0] = (_Float16)a.x; r[1] = (_Float16)a.y;
    r[2] = (_Float16)a.z; r[3] = (_Float16)a.w;
    r[4] = (_Float16)b.x; r[5] = (_Float16)b.y;
    r[6] = (_Float16)b.z; r[7] = (_Float16)b.w;
    return r;
  };

  // one GRU step for gate-arg p (this lane's (chain q, col) value)
  auto gate = [&](const float p) {
    const float ib  = (T == 2) ? rbh_s : p;
    const float s4  = swz_xor<4>(hOwn);    // h of unit U^1
    const float s8  = swz_xor<8>(hOwn);    // h of unit U^2
    const float s12 = swz_xor<12>(hOwn);   // h of unit U^3
    const float i = fmaf(s12, w[3], fmaf(s8, w[2],
                    fmaf(s4, w[1], fmaf(hOwn, w[0], ib))));
    const float sg = fast_rcp(1.0f + fast_exp2(i));  // z(T0) / r(T1)
    const float rb = dpp_f<0x55>(sg);                 // quad's r
    const float ah = fmaf(rb, i, p);                  // T2: tanh arg
    const float th = fmaf(-2.0f, fast_rcp(1.0f + fast_exp2(ah)), 1.0f);
    const float thb = dpp_f<0xAA>(th);                // quad's tanh
    const float zb  = dpp_f<0x00>(sg);                // quad's z
    hOwn = fmaf(zb, hOwn - thb, thb);                 // h_U update (quad-unif)
  };

  auto tile = [&](const float4 (&R)[4]) -> f4v {
    const h8 alo = cvt(R[0], R[1]);
    const h8 ahi = cvt(R[2], R[3]);
    f4v c;
    c[0] = cb; c[1] = cb; c[2] = cb; c[3] = cb;
    c = __builtin_amdgcn_mfma_f32_16x16x32_f16(alo, blo, c, 0, 0, 0);
    c = __builtin_amdgcn_mfma_f32_16x16x32_f16(ahi, bhi, c, 0, 0, 0);
    return c;
  };

  ldt(A0, 0); ldt(A1, 1);
  for (int t = 0; t < SS / 4; t += 2) {
    {
      const f4v c = tile(A0);
      { int tn = t + 2; if (tn > 63) tn = 63; ldt(A0, tn); }
      gate(c[0]); gate(c[1]); gate(c[2]); gate(c[3]);
    }
    {
      const f4v c = tile(A1);
      { int tn = t + 3; if (tn > 63) tn = 63; ldt(A1, tn); }
      gate(c[0]); gate(c[1]); gate(c[2]); gate(c[3]);
    }
  }

  // ---- epilogue: gather h0,h1,h2 (xor swizzles, exec all-on), then col-0
  // lane of each quarter computes dense(3->10)+softmax for its chain.
  const float ha = swz_xor<4>(hOwn);   // on U=0 lane: h1
  const float hb = swz_xor<8>(hOwn);   // on U=0 lane: h2
  if (col == 0) {
    const float h0 = hOwn, h1 = ha, h2 = hb;
    const int c = cbase + q;
    float lg[10];
#pragma unroll
    for (int j = 0; j < 10; ++j)
      lg[j] = dense_b[j] + h0 * dense_w[j] + h1 * dense_w[10 + j] + h2 * dense_w[20 + j];
    float m = lg[0];
#pragma unroll
    for (int j = 1; j < 10; ++j) m = fmaxf(m, lg[j]);
    float e[10];
    float ssum = 0.0f;
#pragma unroll
    for (int j = 0; j < 10; ++j) {
      e[j] = fast_exp2(1.4426950408889634f * (lg[j] - m));
      ssum += e[j];
    }
    const float inv = fast_rcp(ssum);
#pragma unroll
    for (int j = 0; j < 10; ++j) out[(size_t)c * 10 + j] = e[j] * inv;
  }
}

extern "C" void kernel_launch(void* const* d_in, const int* in_sizes, int n_in,
                              void* d_out, int out_size, void* d_ws, size_t ws_size,
                              hipStream_t stream) {
  const float* x      = (const float*)d_in[0];  // [4096,256,64]
  const float* kern   = (const float*)d_in[1];  // [64,9]
  const float* rkern  = (const float*)d_in[2];  // [3,9]
  const float* bias   = (const float*)d_in[3];  // [2,9]
  const float* dw     = (const float*)d_in[4];  // [3,10]
  const float* db     = (const float*)d_in[5];  // [10]
  float* out = (float*)d_out;

  // 4 chains per 64-thread block; 1024 blocks -> 1 wave per SIMD chip-wide.
  fused_gru_kernel<<<BB / 4, 64, 0, stream>>>(x, kern, rkern, bias, dw, db, out);
}

// Round 14
// 54.679 us; speedup vs baseline: 1.6040x; 1.4935x over previous
//
#include <hip/hip_runtime.h>

// Problem constants (from reference setup_inputs)
#define BB 4096   // batch
#define SS 256    // sequence length
#define FF 64     // features
#define GG 9      // 3*U gate width

#define NEG_LOG2E -1.4426950408889634f
#define TWO_LOG2E  2.8853900817779268f

typedef float f2 __attribute__((ext_vector_type(2)));

#if __has_builtin(__builtin_amdgcn_exp2f)
__device__ __forceinline__ float fast_exp2(float x) { return __builtin_amdgcn_exp2f(x); }
#else
__device__ __forceinline__ float fast_exp2(float x) { return exp2f(x); }
#endif
#if __has_builtin(__builtin_amdgcn_rcpf)
__device__ __forceinline__ float fast_rcp(float x) { return __builtin_amdgcn_rcpf(x); }
#else
__device__ __forceinline__ float fast_rcp(float x) { return 1.0f / x; }
#endif

// DPP helper: quad_perm (CTRL<0x100) and row ops (row_ror:N = 0x120+N).
template <int CTRL>
__device__ __forceinline__ float dpp_f(float v) {
  return __int_as_float(
      __builtin_amdgcn_mov_dpp(__float_as_int(v), CTRL, 0xF, 0xF, true));
}

// -----------------------------------------------------------------------------
// Fully fused GRU — R14 = R10 champion (61us) + R12's verified early-select
// reduce. Cross-round evidence (R10 570cy/step vs 196 nominal; R13 MFMA
// slower despite -280 instrs) points at DPP-op issue/hazard cost ~6-8cy at
// 1 wave/SIMD. R14 cuts reduce DPP-adds 36 -> 24:
//   xor1+xor2 quad butterfly (18 DPP, 9 vals) -> every lane holds 9 quad-sums
//   -> EARLY select 3-of-9 by role (6 cndmask, plain VALU)
//   -> ror4+ror8 rotate-accumulate on 3 vals (6 DPP; direction-free, sums
//      all 4 quads; exact primitive verified absmax-0 in R12).
// Everything else byte-identical to R10: depth-8 ring, plain program order
// (R11 stagger was neutral), b1 fold for z/r (R11/R12-verified), Q=1/16.
// -----------------------------------------------------------------------------
__global__ __launch_bounds__(64, 1) void fused_gru_kernel(
    const float* __restrict__ x,           // [B,S,F]
    const float* __restrict__ kernel_w,    // [F,9]
    const float* __restrict__ rec_kernel,  // [3,9]
    const float* __restrict__ bias,        // [2,9]
    const float* __restrict__ dense_w,     // [3,10]
    const float* __restrict__ dense_b,     // [10]
    float* __restrict__ out)               // [B,10]
{
  const int lane = threadIdx.x;        // 0..63
  const int fl   = lane & 15;          // feature-slot within the chain's row
  const int u    = lane & 3;           // gate-unit role within the quad
  const int uc   = (u < 3) ? u : 2;    // lane u==3: clamp unit role (benign)
  const int c    = blockIdx.x * 4 + (lane >> 4);   // chain (batch) id

  // ---- input-projection weights for this lane's 4 features (pre-scaled)
  f2 w01[4], w23[4], w45[4], w67[4];
  float w8[4];
#pragma unroll
  for (int e = 0; e < 4; ++e) {
    const float* kw = kernel_w + (fl * 4 + e) * GG;
    w01[e] = (f2){kw[0] * NEG_LOG2E, kw[1] * NEG_LOG2E};
    w23[e] = (f2){kw[2] * NEG_LOG2E, kw[3] * NEG_LOG2E};
    w45[e] = (f2){kw[4] * NEG_LOG2E, kw[5] * NEG_LOG2E};
    w67[e] = (f2){kw[6] * TWO_LOG2E, kw[7] * TWO_LOG2E};
    w8[e]  = kw[8] * TWO_LOG2E;
  }

  // input bias (+ recurrent bias folded for z/r gates — exact), pre-scaled
  // and SIXTEENTH'd (16-lane reduce restores exactly 1x).
  const float Q = 0.0625f;
  const f2 b01q = {(bias[0] + bias[GG + 0]) * NEG_LOG2E * Q,
                   (bias[1] + bias[GG + 1]) * NEG_LOG2E * Q};
  const f2 b23q = {(bias[2] + bias[GG + 2]) * NEG_LOG2E * Q,
                   (bias[3] + bias[GG + 3]) * NEG_LOG2E * Q};
  const f2 b45q = {(bias[4] + bias[GG + 4]) * NEG_LOG2E * Q,
                   (bias[5] + bias[GG + 5]) * NEG_LOG2E * Q};
  const f2 b67q = {bias[6] * TWO_LOG2E * Q, bias[7] * TWO_LOG2E * Q};
  const float b8q = bias[8] * TWO_LOG2E * Q;

  // recurrent weights for this lane's unit (pre-scaled); only the h-gate's
  // recurrent bias stays separate (it sits inside the r-multiplied term).
  float wz[3], wr[3], wh[3];
#pragma unroll
  for (int hh = 0; hh < 3; ++hh) {
    wz[hh] = rec_kernel[hh * GG + uc]     * NEG_LOG2E;
    wr[hh] = rec_kernel[hh * GG + 3 + uc] * NEG_LOG2E;
    wh[hh] = rec_kernel[hh * GG + 6 + uc] * TWO_LOG2E;
  }
  const float rbh = bias[GG + 6 + uc] * TWO_LOG2E;

  float h0 = 0.0f, h1 = 0.0f, h2 = 0.0f, hprev = 0.0f;

  // per-lane x pointer: row (c,s) = 16 float4s; this lane reads float4 #fl.
  const float4* pc = reinterpret_cast<const float4*>(x) + (size_t)c * SS * 16 + fl;

  // depth-8 register ring (32 VGPRs), named buffers, static indexing
  float4 X0, X1, X2, X3, X4, X5, X6, X7;

  auto step = [&](const float4 v) {
    // projection over this lane's 4 features (20 instrs, f2-packed)
    f2 a01 = b01q, a23 = b23q, a45 = b45q, a67 = b67q;
    float a8 = b8q;
    a01 = v.x * w01[0] + a01; a23 = v.x * w23[0] + a23;
    a45 = v.x * w45[0] + a45; a67 = v.x * w67[0] + a67;
    a8 = fmaf(v.x, w8[0], a8);
    a01 = v.y * w01[1] + a01; a23 = v.y * w23[1] + a23;
    a45 = v.y * w45[1] + a45; a67 = v.y * w67[1] + a67;
    a8 = fmaf(v.y, w8[1], a8);
    a01 = v.z * w01[2] + a01; a23 = v.z * w23[2] + a23;
    a45 = v.z * w45[2] + a45; a67 = v.z * w67[2] + a67;
    a8 = fmaf(v.z, w8[2], a8);
    a01 = v.w * w01[3] + a01; a23 = v.w * w23[3] + a23;
    a45 = v.w * w45[3] + a45; a67 = v.w * w67[3] + a67;
    a8 = fmaf(v.w, w8[3], a8);

    // quad butterfly: after xor1+xor2 every lane holds all 9 quad-sums
    float s0 = a01.x, s1 = a01.y, s2 = a23.x, s3 = a23.y, s4 = a45.x,
          s5 = a45.y, s6 = a67.x, s7 = a67.y, s8 = a8;
    s0 += dpp_f<0xB1>(s0); s1 += dpp_f<0xB1>(s1); s2 += dpp_f<0xB1>(s2);
    s3 += dpp_f<0xB1>(s3); s4 += dpp_f<0xB1>(s4); s5 += dpp_f<0xB1>(s5);
    s6 += dpp_f<0xB1>(s6); s7 += dpp_f<0xB1>(s7); s8 += dpp_f<0xB1>(s8);
    s0 += dpp_f<0x4E>(s0); s1 += dpp_f<0x4E>(s1); s2 += dpp_f<0x4E>(s2);
    s3 += dpp_f<0x4E>(s3); s4 += dpp_f<0x4E>(s4); s5 += dpp_f<0x4E>(s5);
    s6 += dpp_f<0x4E>(s6); s7 += dpp_f<0x4E>(s7); s8 += dpp_f<0x4E>(s8);

    // EARLY role select (3 of 9): ror4/ror8 map lane -> lane with the same
    // role (lane&3), so the per-role values stay aligned (R12-verified).
    float az = (u == 0) ? s0 : ((u == 1) ? s1 : s2);
    float ar = (u == 0) ? s3 : ((u == 1) ? s4 : s5);
    float sh = (u == 0) ? s6 : ((u == 1) ? s7 : s8);

    // cross-quad rotate-accumulate (direction-free full sum over 4 quads)
    az += dpp_f<0x124>(az); ar += dpp_f<0x124>(ar); sh += dpp_f<0x124>(sh);
    az += dpp_f<0x128>(az); ar += dpp_f<0x128>(ar); sh += dpp_f<0x128>(sh);

    // gate chain (absmax-0 verified math; b0+b1 already inside az/ar)
    const float iz = fmaf(h2, wz[2], fmaf(h1, wz[1], fmaf(h0, wz[0], az)));
    const float ir = fmaf(h2, wr[2], fmaf(h1, wr[1], fmaf(h0, wr[0], ar)));
    const float ih = fmaf(h2, wh[2], fmaf(h1, wh[1], fmaf(h0, wh[0], rbh)));
    const float z = fast_rcp(1.0f + fast_exp2(iz));
    const float r = fast_rcp(1.0f + fast_exp2(ir));
    const float t = fmaf(-2.0f, fast_rcp(1.0f + fast_exp2(fmaf(r, ih, sh))), 1.0f);
    const float hn = fmaf(z, hprev - t, t);
    hprev = hn;
    h0 = dpp_f<0x00>(hn);   // quad_perm [0,0,0,0]
    h1 = dpp_f<0x55>(hn);   // quad_perm [1,1,1,1]
    h2 = dpp_f<0xAA>(hn);   // quad_perm [2,2,2,2]
  };

  // branchless prefetch-index clamp: tail re-reads step SS-1 (L1-hit, free)
  auto pf = [&](int sn) -> float4 {
    sn = (sn < SS) ? sn : (SS - 1);
    return pc[(size_t)sn * 16];
  };

  X0 = pf(0); X1 = pf(1); X2 = pf(2); X3 = pf(3);
  X4 = pf(4); X5 = pf(5); X6 = pf(6); X7 = pf(7);

  for (int sg = 0; sg < SS; sg += 8) {
    step(X0); X0 = pf(sg + 8);
    step(X1); X1 = pf(sg + 9);
    step(X2); X2 = pf(sg + 10);
    step(X3); X3 = pf(sg + 11);
    step(X4); X4 = pf(sg + 12);
    step(X5); X5 = pf(sg + 13);
    step(X6); X6 = pf(sg + 14);
    step(X7); X7 = pf(sg + 15);
  }

  // Dense (3 -> 10) + softmax; only quad 0 of each chain row writes.
  if (fl < 4) {
    float lg[10];
#pragma unroll
    for (int j = 0; j < 10; ++j)
      lg[j] = dense_b[j] + h0 * dense_w[j] + h1 * dense_w[10 + j] + h2 * dense_w[20 + j];
    float m = lg[0];
#pragma unroll
    for (int j = 1; j < 10; ++j) m = fmaxf(m, lg[j]);
    float e[10];
    float ssum = 0.0f;
#pragma unroll
    for (int j = 0; j < 10; ++j) {
      e[j] = fast_exp2(1.4426950408889634f * (lg[j] - m));
      ssum += e[j];
    }
    const float inv = fast_rcp(ssum);
#pragma unroll
    for (int j = u; j < 10; j += 4) out[(size_t)c * 10 + j] = e[j] * inv;
  }
}

extern "C" void kernel_launch(void* const* d_in, const int* in_sizes, int n_in,
                              void* d_out, int out_size, void* d_ws, size_t ws_size,
                              hipStream_t stream) {
  const float* x      = (const float*)d_in[0];  // [4096,256,64]
  const float* kern   = (const float*)d_in[1];  // [64,9]
  const float* rkern  = (const float*)d_in[2];  // [3,9]
  const float* bias   = (const float*)d_in[3];  // [2,9]
  const float* dw     = (const float*)d_in[4];  // [3,10]
  const float* db     = (const float*)d_in[5];  // [10]
  float* out = (float*)d_out;

  // 4 chains x 16 lanes per 64-thread block; 1024 blocks -> 1 wave per SIMD
  // on all 1024 SIMDs.
  fused_gru_kernel<<<BB / 4, 64, 0, stream>>>(x, kern, rkern, bias, dw, db, out);
}